// Round 11
// baseline (84.880 us; speedup 1.0000x reference)
//
#include <hip/hip_runtime.h>
#include <math.h>

#define Q_TOTAL 21760
#define QB 16        // queries per sampling block
#define HEAD_IMG_BYTES 1392640   // 21760 * 32 * 2  (one head's transposed image, f16)

typedef _Float16     f16;
typedef short        s16x8 __attribute__((ext_vector_type(8)));
typedef f16          f16x8 __attribute__((ext_vector_type(8)));
typedef f16          f16x4 __attribute__((ext_vector_type(4)));
typedef f16          f16x2 __attribute__((ext_vector_type(2)));
typedef __bf16       bfv8  __attribute__((ext_vector_type(8)));
typedef float        f32x4 __attribute__((ext_vector_type(4)));
typedef float        f32x2 __attribute__((ext_vector_type(2)));
typedef unsigned int u32x4 __attribute__((ext_vector_type(4)));
typedef unsigned int u32x2 __attribute__((ext_vector_type(2)));

// pack 8 floats -> 8 bf16 (RNE; compiler emits v_cvt_pk_bf16_f32)
__device__ __forceinline__ s16x8 pack8(float4 a, float4 b) {
    bfv8 t;
    t[0] = (__bf16)a.x; t[1] = (__bf16)a.y; t[2] = (__bf16)a.z; t[3] = (__bf16)a.w;
    t[4] = (__bf16)b.x; t[5] = (__bf16)b.y; t[6] = (__bf16)b.z; t[7] = (__bf16)b.w;
    return __builtin_bit_cast(s16x8, t);
}

// ---------------------------------------------------------------------------
// Convert the 4 weight matrices to bf16 + build concat bias [b_off|b_attn].
// dst layout: [W_off 65536 | W_attn 32768 | W_val 65536 | W_out 65536]
// ---------------------------------------------------------------------------
__global__ __launch_bounds__(256) void cvt_weights(
    const float* __restrict__ Woff, const float* __restrict__ Wattn,
    const float* __restrict__ Wval, const float* __restrict__ Wout,
    const float* __restrict__ boff, const float* __restrict__ battn,
    unsigned short* __restrict__ dst, float* __restrict__ bias_cat)
{
    if (blockIdx.x == 224) {
        const int t = threadIdx.x;
        bias_cat[t] = boff[t];
        if (t < 128) bias_cat[256 + t] = battn[t];
        return;
    }
    const int e = blockIdx.x * 1024 + threadIdx.x * 4;
    const float* src; int base;
    if (e < 65536)       { src = Woff;  base = 0; }
    else if (e < 98304)  { src = Wattn; base = 65536; }
    else if (e < 163840) { src = Wval;  base = 98304; }
    else                 { src = Wout;  base = 163840; }
    float4 v = *(const float4*)(src + (e - base));
    ushort4 o;
    o.x = __builtin_bit_cast(unsigned short, (__bf16)v.x);
    o.y = __builtin_bit_cast(unsigned short, (__bf16)v.y);
    o.z = __builtin_bit_cast(unsigned short, (__bf16)v.z);
    o.w = __builtin_bit_cast(unsigned short, (__bf16)v.w);
    *(ushort4*)(dst + e) = o;
}

// ---------------------------------------------------------------------------
// Fused projection GEMM: BM=128, BN=128 slab, BK=32, 256 threads = 4 waves.
// grid (170, 5): slab 0-1: A=input_flatten, W=W_val slab -> value_t (f16, VT)
//                slab 2-4: A=query, W=[W_off|W_attn] slab -> offattn (f16)
// Staging: r9-proven mapping (4 threads/row, rows {sr, sr+64}): 2-way free.
// Weights pre-converted bf16. Frag reads 2-way free (rows r,r+8 alias).
// ---------------------------------------------------------------------------
__global__ __launch_bounds__(256) void gemm_proj(
    const float* __restrict__ input_flatten,
    const float* __restrict__ query,
    const unsigned short* __restrict__ w16,
    const float* __restrict__ b_val,
    const float* __restrict__ bias_cat,
    f16* __restrict__ value_t,
    f16* __restrict__ offattn)
{
    constexpr int K = 256;
    __shared__ unsigned short As[128 * 32];
    __shared__ unsigned short Bs[128 * 32];

    const int tid  = threadIdx.x;
    const int lane = tid & 63;
    const int wv   = tid >> 6;
    const int wr   = wv >> 1, wc = wv & 1;
    const int rowBase = blockIdx.x * 128;
    const int slab = blockIdx.y;

    const float* A32 = (slab < 2) ? input_flatten : query;
    int wbase;
    switch (slab) {
        case 0:  wbase = 98304;  break;   // W_val rows 0-127
        case 1:  wbase = 131072; break;   // W_val rows 128-255
        case 2:  wbase = 0;      break;   // W_off rows 0-127
        case 3:  wbase = 32768;  break;   // W_off rows 128-255
        default: wbase = 65536;  break;   // W_attn
    }
    const unsigned short* Wp0 = w16 + wbase;
    const float* bias = (slab < 2) ? (b_val + slab * 128) : (bias_cat + (slab - 2) * 128);

    const int sr   = tid >> 2;       // 0..63
    const int skq  = (tid & 3) * 8;  // elem offset along K
    const int sby  = (tid & 3) * 16; // byte slot within 64B row

    f32x4 acc[4][4];
#pragma unroll
    for (int i = 0; i < 4; i++)
#pragma unroll
        for (int j = 0; j < 4; j++) acc[i][j] = (f32x4){0.f, 0.f, 0.f, 0.f};

    const float* ApA = A32 + (size_t)(rowBase + sr) * K + skq;
    const float* ApB = A32 + (size_t)(rowBase + sr + 64) * K + skq;
    const unsigned short* WpA = Wp0 + (size_t)sr * K + skq;
    const unsigned short* WpB = Wp0 + (size_t)(sr + 64) * K + skq;

    for (int kt = 0; kt < K; kt += 32) {
        s16x8 a0 = pack8(*(const float4*)(ApA + kt), *(const float4*)(ApA + kt + 4));
        s16x8 a1 = pack8(*(const float4*)(ApB + kt), *(const float4*)(ApB + kt + 4));
        s16x8 b0 = *(const s16x8*)(WpA + kt);
        s16x8 b1 = *(const s16x8*)(WpB + kt);
        __syncthreads();
        // rows sr and sr+64: (sr+64)&7 == sr&7, so same XOR term
        *(s16x8*)((char*)As + (((sr      ) * 64 + sby) ^ ((sr & 7) << 4))) = a0;
        *(s16x8*)((char*)As + (((sr + 64) * 64 + sby) ^ ((sr & 7) << 4))) = a1;
        *(s16x8*)((char*)Bs + (((sr      ) * 64 + sby) ^ ((sr & 7) << 4))) = b0;
        *(s16x8*)((char*)Bs + (((sr + 64) * 64 + sby) ^ ((sr & 7) << 4))) = b1;
        __syncthreads();
        s16x8 af[4], bf[4];
#pragma unroll
        for (int mi = 0; mi < 4; mi++) {
            const int row = wr * 64 + mi * 16 + (lane & 15);
            af[mi] = *(const s16x8*)((char*)As + ((row * 64 + (lane >> 4) * 16) ^ ((row & 7) << 4)));
        }
#pragma unroll
        for (int ni = 0; ni < 4; ni++) {
            const int row = wc * 64 + ni * 16 + (lane & 15);
            bf[ni] = *(const s16x8*)((char*)Bs + ((row * 64 + (lane >> 4) * 16) ^ ((row & 7) << 4)));
        }
#pragma unroll
        for (int ni = 0; ni < 4; ni++)
#pragma unroll
            for (int mi = 0; mi < 4; mi++)
                acc[mi][ni] = __builtin_amdgcn_mfma_f32_16x16x32_bf16(af[mi], bf[ni], acc[mi][ni], 0, 0, 0);
    }

#pragma unroll
    for (int ni = 0; ni < 4; ni++) {
        const int localcol = wc * 64 + ni * 16 + (lane & 15);
        const float bv = bias[localcol];
#pragma unroll
        for (int mi = 0; mi < 4; mi++) {
            const int r0 = rowBase + wr * 64 + mi * 16 + (lane >> 4) * 4;
#pragma unroll
            for (int j = 0; j < 4; j++) {
                const float v = acc[mi][ni][j] + bv;
                const int row = r0 + j;
                if (slab < 2) {
                    const int col = slab * 128 + localcol;
                    value_t[((size_t)(col >> 5) * Q_TOTAL + row) * 32 + (col & 31)] = (f16)v;
                } else {
                    const int col = (slab - 2) * 128 + localcol;
                    offattn[(size_t)row * 384 + col] = (f16)v;
                }
            }
        }
    }
}

// ---------------------------------------------------------------------------
// Output GEMM: out[Q][256] f32 = sampled(bf16) @ W_out^T + b_out.
// BM=128, BN=128, grid (170, 2). Same staging/frag patterns as gemm_proj.
// ---------------------------------------------------------------------------
__global__ __launch_bounds__(256) void gemm_out(
    const unsigned short* __restrict__ A16,      // sampled bf16 [Q][256]
    const unsigned short* __restrict__ W16,      // W_out bf16 [256][256]
    const float* __restrict__ bias,
    float* __restrict__ C)
{
    constexpr int K = 256;
    __shared__ unsigned short As[128 * 32];
    __shared__ unsigned short Bs[128 * 32];

    const int tid  = threadIdx.x;
    const int lane = tid & 63;
    const int wv   = tid >> 6;
    const int wr   = wv >> 1, wc = wv & 1;
    const int rowBase = blockIdx.x * 128;
    const int colBase = blockIdx.y * 128;

    const int sr   = tid >> 2;
    const int skq  = (tid & 3) * 8;
    const int sby  = (tid & 3) * 16;

    f32x4 acc[4][4];
#pragma unroll
    for (int i = 0; i < 4; i++)
#pragma unroll
        for (int j = 0; j < 4; j++) acc[i][j] = (f32x4){0.f, 0.f, 0.f, 0.f};

    const unsigned short* ApA = A16 + (size_t)(rowBase + sr) * K + skq;
    const unsigned short* ApB = A16 + (size_t)(rowBase + sr + 64) * K + skq;
    const unsigned short* WpA = W16 + (size_t)(colBase + sr) * K + skq;
    const unsigned short* WpB = W16 + (size_t)(colBase + sr + 64) * K + skq;

    for (int kt = 0; kt < K; kt += 32) {
        s16x8 a0 = *(const s16x8*)(ApA + kt);
        s16x8 a1 = *(const s16x8*)(ApB + kt);
        s16x8 b0 = *(const s16x8*)(WpA + kt);
        s16x8 b1 = *(const s16x8*)(WpB + kt);
        __syncthreads();
        *(s16x8*)((char*)As + (((sr      ) * 64 + sby) ^ ((sr & 7) << 4))) = a0;
        *(s16x8*)((char*)As + (((sr + 64) * 64 + sby) ^ ((sr & 7) << 4))) = a1;
        *(s16x8*)((char*)Bs + (((sr      ) * 64 + sby) ^ ((sr & 7) << 4))) = b0;
        *(s16x8*)((char*)Bs + (((sr + 64) * 64 + sby) ^ ((sr & 7) << 4))) = b1;
        __syncthreads();
        s16x8 af[4], bf[4];
#pragma unroll
        for (int mi = 0; mi < 4; mi++) {
            const int row = wr * 64 + mi * 16 + (lane & 15);
            af[mi] = *(const s16x8*)((char*)As + ((row * 64 + (lane >> 4) * 16) ^ ((row & 7) << 4)));
        }
#pragma unroll
        for (int ni = 0; ni < 4; ni++) {
            const int row = wc * 64 + ni * 16 + (lane & 15);
            bf[ni] = *(const s16x8*)((char*)Bs + ((row * 64 + (lane >> 4) * 16) ^ ((row & 7) << 4)));
        }
#pragma unroll
        for (int ni = 0; ni < 4; ni++)
#pragma unroll
            for (int mi = 0; mi < 4; mi++)
                acc[mi][ni] = __builtin_amdgcn_mfma_f32_16x16x32_bf16(af[mi], bf[ni], acc[mi][ni], 0, 0, 0);
    }

#pragma unroll
    for (int ni = 0; ni < 4; ni++) {
        const int col = colBase + wc * 64 + ni * 16 + (lane & 15);
        const float bv = bias[col];
#pragma unroll
        for (int mi = 0; mi < 4; mi++) {
            const int r0 = rowBase + wr * 64 + mi * 16 + (lane >> 4) * 4;
#pragma unroll
            for (int j = 0; j < 4; j++)
                C[(size_t)(r0 + j) * 256 + col] = acc[mi][ni][j] + bv;
        }
    }
}

// ---------------------------------------------------------------------------
// Sampling: block = 16 queries x 2 heads (256 threads).  [unchanged from r9]
// At its structural floor (~39 us): random-gather L2 throughput + vmem issue.
// ---------------------------------------------------------------------------
__global__ __launch_bounds__(256) void sample_kernel(
    const f16* __restrict__ value_t,             // [8][Q][32] f16
    const f16* __restrict__ offattn,             // [Q][384] f16
    const float* __restrict__ refpts,            // [Q][4][2] f32
    unsigned short* __restrict__ sampled)        // [Q][256] bf16
{
    __shared__ __attribute__((aligned(16))) unsigned s_iw[32 * 132];

    const int tid   = threadIdx.x;
    const int qt    = blockIdx.x >> 2;
    const int hp    = blockIdx.x & 3;
    const int qbase = qt * QB;

    // ---------------- phase 1 ----------------
    {
        const int q  = tid >> 4;
        const int h  = (tid >> 3) & 1;
        const int l  = (tid >> 1) & 3;
        const int ph = tid & 1;
        const int H  = hp * 2 + h;
        const int g  = tid >> 3;         // q*2 + h
        const f16* oa = offattn + (size_t)(qbase + q) * 384;

        f16x2 lgh = *(const f16x2*)(oa + 256 + H * 16 + l * 4 + ph * 2);
        const float lg0 = (float)lgh[0], lg1 = (float)lgh[1];
        float m = fmaxf(lg0, lg1);
        m = fmaxf(m, __shfl_xor(m, 1));
        m = fmaxf(m, __shfl_xor(m, 2));
        m = fmaxf(m, __shfl_xor(m, 4));
        float e0 = __expf(lg0 - m), e1 = __expf(lg1 - m);
        float s = e0 + e1;
        s += __shfl_xor(s, 1);
        s += __shfl_xor(s, 2);
        s += __shfl_xor(s, 4);
        const float inv = 1.f / s;
        const float aw2[2] = {e0 * inv, e1 * inv};

        f16x4 offh = *(const f16x4*)(oa + H * 32 + l * 8 + ph * 4);
        f32x2 rp = *(const f32x2*)(refpts + (size_t)(qbase + q) * 8 + l * 2);

        const int   SZ[4] = {128, 64, 32, 16};
        const int   ST[4] = {0, 16384, 20480, 21504};
        const int   W_ = SZ[l], START = ST[l];
        const float S = (float)W_;

        unsigned* dst = &s_iw[g * 132 + (l * 4 + ph * 2) * 8];
#pragma unroll
        for (int c = 0; c < 2; c++) {
            const float ox = (float)offh[c * 2], oy = (float)offh[c * 2 + 1];
            const float a = aw2[c];
            const float gx = fmaf(rp[0], S, ox) - 0.5f;
            const float gy = fmaf(rp[1], S, oy) - 0.5f;
            const float x0f = floorf(gx), y0f = floorf(gy);
            const float lx = gx - x0f, ly = gy - y0f;
            const int x0 = (int)x0f, y0 = (int)y0f;
            const int xs  = min(max(x0, 0), W_ - 2);
            const int sft = xs - x0;
            const float wx0 = (x0 >= 0 && x0 < W_) ? (1.f - lx) : 0.f;
            const float wx1 = (x0 + 1 >= 0 && x0 + 1 < W_) ? lx : 0.f;
            const float wxA = (sft == 0) ? wx0 : ((sft == 1) ? wx1 : 0.f);
            const float wxB = (sft == 0) ? wx1 : ((sft == -1) ? wx0 : 0.f);
            const int y1 = y0 + 1;
            const int y0c = min(max(y0, 0), W_ - 1);
            const int y1c = min(max(y1, 0), W_ - 1);
            const float wy0a = (((y0 >= 0) && (y0 < W_)) ? (1.f - ly) : 0.f) * a;
            const float wy1a = (((y1 >= 0) && (y1 < W_)) ? ly : 0.f) * a;
            const unsigned o0 = (unsigned)((START + y0c * W_ + xs) * 64);
            const unsigned o1 = (unsigned)((START + y1c * W_ + xs) * 64);
            u32x4 r0, r1;
            r0[0] = o0;      r0[1] = o1;
            r0[2] = __float_as_uint(wy0a * wxA);
            r0[3] = __float_as_uint(wy1a * wxA);
            r1[0] = o0 + 64; r1[1] = o1 + 64;
            r1[2] = __float_as_uint(wy0a * wxB);
            r1[3] = __float_as_uint(wy1a * wxB);
            *(u32x4*)(dst + c * 8)     = r0;
            *(u32x4*)(dst + c * 8 + 4) = r1;
        }
    }
    __syncthreads();

    // ---------------- phase 2 ----------------
    {
        const int d8 = tid & 3;
        const int xc = (tid >> 2) & 1;
        const int g  = tid >> 3;          // q*2 + h
        const int q  = g >> 1;
        const int h  = g & 1;
        const int H  = hp * 2 + h;
        const unsigned vbase = (unsigned)(H * HEAD_IMG_BYTES) + (unsigned)(d8 * 16);
        const char* vt = (const char*)value_t;
        const unsigned* iw = &s_iw[g * 132 + xc * 4];

        float acc[8] = {0.f, 0.f, 0.f, 0.f, 0.f, 0.f, 0.f, 0.f};
#pragma unroll
        for (int half = 0; half < 2; half++) {
            u32x2 off[8];
#pragma unroll
            for (int p = 0; p < 8; p++)
                off[p] = *(const u32x2*)(iw + (half * 8 + p) * 8);
            f16x8 v0[8], v1[8];
#pragma unroll
            for (int p = 0; p < 8; p++) {
                v0[p] = *(const f16x8*)(vt + (size_t)(vbase + off[p][0]));
                v1[p] = *(const f16x8*)(vt + (size_t)(vbase + off[p][1]));
            }
#pragma unroll
            for (int p = 0; p < 8; p++) {
                const f32x2 w = *(const f32x2*)(iw + (half * 8 + p) * 8 + 2);
#pragma unroll
                for (int r = 0; r < 8; r++) {
                    acc[r] = fmaf((float)v0[p][r], w[0], acc[r]);   // v_fma_mix_f32
                    acc[r] = fmaf((float)v1[p][r], w[1], acc[r]);
                }
            }
        }
#pragma unroll
        for (int j = 0; j < 8; j++) acc[j] += __shfl_xor(acc[j], 4);

        if (xc == 0) {
            s16x8 o = pack8(make_float4(acc[0], acc[1], acc[2], acc[3]),
                            make_float4(acc[4], acc[5], acc[6], acc[7]));
            *(s16x8*)(sampled + (size_t)(qbase + q) * 256 + H * 32 + d8 * 8) = o;
        }
    }
}

// ---------------------------------------------------------------------------
extern "C" void kernel_launch(void* const* d_in, const int* in_sizes, int n_in,
                              void* d_out, int out_size, void* d_ws, size_t ws_size,
                              hipStream_t stream) {
    const float* query  = (const float*)d_in[0];
    const float* refpts = (const float*)d_in[1];
    const float* input_flatten = (const float*)d_in[2];
    const float* W_off  = (const float*)d_in[5];
    const float* b_off  = (const float*)d_in[6];
    const float* W_attn = (const float*)d_in[7];
    const float* b_attn = (const float*)d_in[8];
    const float* W_val  = (const float*)d_in[9];
    const float* b_val  = (const float*)d_in[10];
    const float* W_out  = (const float*)d_in[11];
    const float* b_out  = (const float*)d_in[12];
    float* out = (float*)d_out;

    char* ws = (char*)d_ws;
    f16*            value_t = (f16*)ws;                                    // 8*Q*32 f16   = 11141120 B
    f16*            offattn = (f16*)(ws + 11141120);                       // Q*384 f16    = 16711680 B
    unsigned short* sampled = (unsigned short*)(ws + 27852800);            // Q*256 bf16   = 11141120 B
    unsigned short* w16     = (unsigned short*)(ws + 38993920);            // 229376 bf16
    float*          bias_cat= (float*)(ws + 39452672);                     // 384 f32

    cvt_weights<<<225, 256, 0, stream>>>(W_off, W_attn, W_val, W_out, b_off, b_attn, w16, bias_cat);

    // value_t + offattn in one dispatch (128x128 tiles, 5 slabs)
    gemm_proj<<<dim3(170, 5), 256, 0, stream>>>(input_flatten, query, w16,
                                                b_val, bias_cat, value_t, offattn);
    // bilinear sampling + attention-weighted sum
    sample_kernel<<<dim3((Q_TOTAL / QB) * 4), 256, 0, stream>>>(value_t, offattn, refpts, sampled);
    // out = sampled @ W_out^T + b_out
    gemm_out<<<dim3(170, 2), 256, 0, stream>>>(sampled, w16 + 163840, b_out, out);
}

// Round 12
// 80.158 us; speedup vs baseline: 1.0589x; 1.0589x over previous
//
#include <hip/hip_runtime.h>
#include <math.h>

#define Q_TOTAL 21760
#define QB 16        // queries per sampling block
#define HEAD_IMG_BYTES 1392640   // 21760 * 32 * 2  (one head's transposed image, f16)

typedef _Float16     f16;
typedef short        s16x8 __attribute__((ext_vector_type(8)));
typedef f16          f16x8 __attribute__((ext_vector_type(8)));
typedef f16          f16x4 __attribute__((ext_vector_type(4)));
typedef f16          f16x2 __attribute__((ext_vector_type(2)));
typedef __bf16       bfv8  __attribute__((ext_vector_type(8)));
typedef float        f32x4 __attribute__((ext_vector_type(4)));
typedef float        f32x2 __attribute__((ext_vector_type(2)));
typedef unsigned int u32x4 __attribute__((ext_vector_type(4)));
typedef unsigned int u32x2 __attribute__((ext_vector_type(2)));

// pack 8 floats -> 8 bf16 (RNE; compiler emits v_cvt_pk_bf16_f32)
__device__ __forceinline__ s16x8 pack8(float4 a, float4 b) {
    bfv8 t;
    t[0] = (__bf16)a.x; t[1] = (__bf16)a.y; t[2] = (__bf16)a.z; t[3] = (__bf16)a.w;
    t[4] = (__bf16)b.x; t[5] = (__bf16)b.y; t[6] = (__bf16)b.z; t[7] = (__bf16)b.w;
    return __builtin_bit_cast(s16x8, t);
}

// ---------------------------------------------------------------------------
// Convert the 4 weight matrices to bf16 + build concat bias [b_off|b_attn].
// dst layout: [W_off 65536 | W_attn 32768 | W_val 65536 | W_out 65536]
// ---------------------------------------------------------------------------
__global__ __launch_bounds__(256) void cvt_weights(
    const float* __restrict__ Woff, const float* __restrict__ Wattn,
    const float* __restrict__ Wval, const float* __restrict__ Wout,
    const float* __restrict__ boff, const float* __restrict__ battn,
    unsigned short* __restrict__ dst, float* __restrict__ bias_cat)
{
    if (blockIdx.x == 224) {
        const int t = threadIdx.x;
        bias_cat[t] = boff[t];
        if (t < 128) bias_cat[256 + t] = battn[t];
        return;
    }
    const int e = blockIdx.x * 1024 + threadIdx.x * 4;
    const float* src; int base;
    if (e < 65536)       { src = Woff;  base = 0; }
    else if (e < 98304)  { src = Wattn; base = 65536; }
    else if (e < 163840) { src = Wval;  base = 98304; }
    else                 { src = Wout;  base = 163840; }
    float4 v = *(const float4*)(src + (e - base));
    ushort4 o;
    o.x = __builtin_bit_cast(unsigned short, (__bf16)v.x);
    o.y = __builtin_bit_cast(unsigned short, (__bf16)v.y);
    o.z = __builtin_bit_cast(unsigned short, (__bf16)v.z);
    o.w = __builtin_bit_cast(unsigned short, (__bf16)v.w);
    *(ushort4*)(dst + e) = o;
}

// ---------------------------------------------------------------------------
// Fused projection GEMM: BM=64, BN=128 slab, BK=32, 256 threads = 4 waves.
// grid (340, 5): slab 0-1: A=input_flatten, W=W_val slab -> value_t (f16, VT)
//                slab 2-4: A=query, W=[W_off|W_attn]     -> offattn (f16)
// 1700 blocks = 6.6/CU: best packing of any config tried.
// r8-proven staging (4 threads/row, slot tid&3) + XOR swizzle: conflicts free.
// ---------------------------------------------------------------------------
__global__ __launch_bounds__(256) void gemm_proj(
    const float* __restrict__ input_flatten,
    const float* __restrict__ query,
    const unsigned short* __restrict__ w16,
    const float* __restrict__ b_val,
    const float* __restrict__ bias_cat,
    f16* __restrict__ value_t,
    f16* __restrict__ offattn)
{
    constexpr int K = 256, BM = 64, BN = 128;
    constexpr int NB2 = BN / 2;          // 64 cols per wave-col
    constexpr int NF = NB2 / 16;         // 4 frags
    __shared__ unsigned short As[BM * 32];
    __shared__ unsigned short Bs[BN * 32];

    const int tid  = threadIdx.x;
    const int lane = tid & 63;
    const int wv   = tid >> 6;
    const int wr   = wv >> 1, wc = wv & 1;
    const int rowBase = blockIdx.x * BM;
    const int slab = blockIdx.y;

    const float* A32 = (slab < 2) ? input_flatten : query;
    int wbase;
    switch (slab) {
        case 0:  wbase = 98304;  break;   // W_val rows 0-127
        case 1:  wbase = 131072; break;   // W_val rows 128-255
        case 2:  wbase = 0;      break;   // W_off rows 0-127
        case 3:  wbase = 32768;  break;   // W_off rows 128-255
        default: wbase = 65536;  break;   // W_attn
    }
    const unsigned short* Wp0 = w16 + wbase;
    const float* bias = (slab < 2) ? (b_val + slab * 128) : (bias_cat + (slab - 2) * 128);

    const int sr    = tid >> 2;          // staging row 0..63
    const int skq   = (tid & 3) * 8;     // 8 elems per thread along K
    const int sslot = (tid & 3) * 16;    // byte slot within 64B row

    f32x4 acc[2][NF];
#pragma unroll
    for (int i = 0; i < 2; i++)
#pragma unroll
        for (int j = 0; j < NF; j++) acc[i][j] = (f32x4){0.f, 0.f, 0.f, 0.f};

    const float* Ap = A32 + (size_t)(rowBase + sr) * K + skq;

    for (int kt = 0; kt < K; kt += 32) {
        s16x8 aval = pack8(*(const float4*)(Ap + kt), *(const float4*)(Ap + kt + 4));
        s16x8 bval[2];
#pragma unroll
        for (int c = 0; c < 2; c++) {
            const unsigned short* p = Wp0 + (size_t)(c * 64 + sr) * K + kt + skq;
            bval[c] = *(const s16x8*)p;
        }
        __syncthreads();
        *(s16x8*)(As + (((sr * 64 + sslot) ^ ((sr & 7) << 4)) >> 1)) = aval;
#pragma unroll
        for (int c = 0; c < 2; c++) {
            const int row = c * 64 + sr;
            *(s16x8*)(Bs + (((row * 64 + sslot) ^ ((row & 7) << 4)) >> 1)) = bval[c];
        }
        __syncthreads();
        s16x8 af[2];
#pragma unroll
        for (int mi = 0; mi < 2; mi++) {
            const int row = wr * 32 + mi * 16 + (lane & 15);
            af[mi] = *(const s16x8*)(As + (((row * 64 + (lane >> 4) * 16) ^ ((row & 7) << 4)) >> 1));
        }
#pragma unroll
        for (int ni = 0; ni < NF; ni++) {
            const int row = wc * NB2 + ni * 16 + (lane & 15);
            s16x8 bfrag = *(const s16x8*)(Bs + (((row * 64 + (lane >> 4) * 16) ^ ((row & 7) << 4)) >> 1));
#pragma unroll
            for (int mi = 0; mi < 2; mi++)
                acc[mi][ni] = __builtin_amdgcn_mfma_f32_16x16x32_bf16(af[mi], bfrag, acc[mi][ni], 0, 0, 0);
        }
    }

#pragma unroll
    for (int ni = 0; ni < NF; ni++) {
        const int localcol = wc * NB2 + ni * 16 + (lane & 15);
        const float bv = bias[localcol];
#pragma unroll
        for (int mi = 0; mi < 2; mi++) {
            const int r0 = rowBase + wr * 32 + mi * 16 + (lane >> 4) * 4;
#pragma unroll
            for (int j = 0; j < 4; j++) {
                const float v = acc[mi][ni][j] + bv;
                const int row = r0 + j;
                if (slab < 2) {
                    const int col = slab * 128 + localcol;
                    value_t[((size_t)(col >> 5) * Q_TOTAL + row) * 32 + (col & 31)] = (f16)v;
                } else {
                    const int col = (slab - 2) * 128 + localcol;
                    offattn[(size_t)row * 384 + col] = (f16)v;
                }
            }
        }
    }
}

// ---------------------------------------------------------------------------
// Output GEMM: out[Q][256] f32 = sampled(bf16) @ W_out^T + b_out.
// BM=64, BN=128 slab, grid (340, 2) — r8's proven config.
// ---------------------------------------------------------------------------
__global__ __launch_bounds__(256) void gemm_out(
    const unsigned short* __restrict__ A16,      // sampled bf16 [Q][256]
    const unsigned short* __restrict__ W16,      // W_out bf16 [256][256]
    const float* __restrict__ bias,
    float* __restrict__ C)
{
    constexpr int K = 256, BM = 64, BN = 128;
    constexpr int NB2 = BN / 2;
    constexpr int NF = NB2 / 16;
    __shared__ unsigned short As[BM * 32];
    __shared__ unsigned short Bs[BN * 32];

    const int tid  = threadIdx.x;
    const int lane = tid & 63;
    const int wv   = tid >> 6;
    const int wr   = wv >> 1, wc = wv & 1;
    const int rowBase = blockIdx.x * BM;
    const int colBase = blockIdx.y * BN;

    const int sr    = tid >> 2;
    const int skq   = (tid & 3) * 8;
    const int sslot = (tid & 3) * 16;

    f32x4 acc[2][NF];
#pragma unroll
    for (int i = 0; i < 2; i++)
#pragma unroll
        for (int j = 0; j < NF; j++) acc[i][j] = (f32x4){0.f, 0.f, 0.f, 0.f};

    const unsigned short* Ap = A16 + (size_t)(rowBase + sr) * K + skq;

    for (int kt = 0; kt < K; kt += 32) {
        s16x8 aval = *(const s16x8*)(Ap + kt);
        s16x8 bval[2];
#pragma unroll
        for (int c = 0; c < 2; c++) {
            const unsigned short* p = W16 + (size_t)(colBase + c * 64 + sr) * K + kt + skq;
            bval[c] = *(const s16x8*)p;
        }
        __syncthreads();
        *(s16x8*)(As + (((sr * 64 + sslot) ^ ((sr & 7) << 4)) >> 1)) = aval;
#pragma unroll
        for (int c = 0; c < 2; c++) {
            const int row = c * 64 + sr;
            *(s16x8*)(Bs + (((row * 64 + sslot) ^ ((row & 7) << 4)) >> 1)) = bval[c];
        }
        __syncthreads();
        s16x8 af[2];
#pragma unroll
        for (int mi = 0; mi < 2; mi++) {
            const int row = wr * 32 + mi * 16 + (lane & 15);
            af[mi] = *(const s16x8*)(As + (((row * 64 + (lane >> 4) * 16) ^ ((row & 7) << 4)) >> 1));
        }
#pragma unroll
        for (int ni = 0; ni < NF; ni++) {
            const int row = wc * NB2 + ni * 16 + (lane & 15);
            s16x8 bfrag = *(const s16x8*)(Bs + (((row * 64 + (lane >> 4) * 16) ^ ((row & 7) << 4)) >> 1));
#pragma unroll
            for (int mi = 0; mi < 2; mi++)
                acc[mi][ni] = __builtin_amdgcn_mfma_f32_16x16x32_bf16(af[mi], bfrag, acc[mi][ni], 0, 0, 0);
        }
    }

#pragma unroll
    for (int ni = 0; ni < NF; ni++) {
        const int col = colBase + wc * NB2 + ni * 16 + (lane & 15);
        const float bv = bias[col];
#pragma unroll
        for (int mi = 0; mi < 2; mi++) {
            const int r0 = rowBase + wr * 32 + mi * 16 + (lane >> 4) * 4;
#pragma unroll
            for (int j = 0; j < 4; j++)
                C[(size_t)(r0 + j) * 256 + col] = acc[mi][ni][j] + bv;
        }
    }
}

// ---------------------------------------------------------------------------
// Sampling: block = 16 queries x 2 heads (256 threads).  [unchanged from r9]
// At its structural floor (~39 us): random-gather L2 throughput.
// ---------------------------------------------------------------------------
__global__ __launch_bounds__(256) void sample_kernel(
    const f16* __restrict__ value_t,             // [8][Q][32] f16
    const f16* __restrict__ offattn,             // [Q][384] f16
    const float* __restrict__ refpts,            // [Q][4][2] f32
    unsigned short* __restrict__ sampled)        // [Q][256] bf16
{
    __shared__ __attribute__((aligned(16))) unsigned s_iw[32 * 132];

    const int tid   = threadIdx.x;
    const int qt    = blockIdx.x >> 2;
    const int hp    = blockIdx.x & 3;
    const int qbase = qt * QB;

    // ---------------- phase 1 ----------------
    {
        const int q  = tid >> 4;
        const int h  = (tid >> 3) & 1;
        const int l  = (tid >> 1) & 3;
        const int ph = tid & 1;
        const int H  = hp * 2 + h;
        const int g  = tid >> 3;         // q*2 + h
        const f16* oa = offattn + (size_t)(qbase + q) * 384;

        f16x2 lgh = *(const f16x2*)(oa + 256 + H * 16 + l * 4 + ph * 2);
        const float lg0 = (float)lgh[0], lg1 = (float)lgh[1];
        float m = fmaxf(lg0, lg1);
        m = fmaxf(m, __shfl_xor(m, 1));
        m = fmaxf(m, __shfl_xor(m, 2));
        m = fmaxf(m, __shfl_xor(m, 4));
        float e0 = __expf(lg0 - m), e1 = __expf(lg1 - m);
        float s = e0 + e1;
        s += __shfl_xor(s, 1);
        s += __shfl_xor(s, 2);
        s += __shfl_xor(s, 4);
        const float inv = 1.f / s;
        const float aw2[2] = {e0 * inv, e1 * inv};

        f16x4 offh = *(const f16x4*)(oa + H * 32 + l * 8 + ph * 4);
        f32x2 rp = *(const f32x2*)(refpts + (size_t)(qbase + q) * 8 + l * 2);

        const int   SZ[4] = {128, 64, 32, 16};
        const int   ST[4] = {0, 16384, 20480, 21504};
        const int   W_ = SZ[l], START = ST[l];
        const float S = (float)W_;

        unsigned* dst = &s_iw[g * 132 + (l * 4 + ph * 2) * 8];
#pragma unroll
        for (int c = 0; c < 2; c++) {
            const float ox = (float)offh[c * 2], oy = (float)offh[c * 2 + 1];
            const float a = aw2[c];
            const float gx = fmaf(rp[0], S, ox) - 0.5f;
            const float gy = fmaf(rp[1], S, oy) - 0.5f;
            const float x0f = floorf(gx), y0f = floorf(gy);
            const float lx = gx - x0f, ly = gy - y0f;
            const int x0 = (int)x0f, y0 = (int)y0f;
            const int xs  = min(max(x0, 0), W_ - 2);
            const int sft = xs - x0;
            const float wx0 = (x0 >= 0 && x0 < W_) ? (1.f - lx) : 0.f;
            const float wx1 = (x0 + 1 >= 0 && x0 + 1 < W_) ? lx : 0.f;
            const float wxA = (sft == 0) ? wx0 : ((sft == 1) ? wx1 : 0.f);
            const float wxB = (sft == 0) ? wx1 : ((sft == -1) ? wx0 : 0.f);
            const int y1 = y0 + 1;
            const int y0c = min(max(y0, 0), W_ - 1);
            const int y1c = min(max(y1, 0), W_ - 1);
            const float wy0a = (((y0 >= 0) && (y0 < W_)) ? (1.f - ly) : 0.f) * a;
            const float wy1a = (((y1 >= 0) && (y1 < W_)) ? ly : 0.f) * a;
            const unsigned o0 = (unsigned)((START + y0c * W_ + xs) * 64);
            const unsigned o1 = (unsigned)((START + y1c * W_ + xs) * 64);
            u32x4 r0, r1;
            r0[0] = o0;      r0[1] = o1;
            r0[2] = __float_as_uint(wy0a * wxA);
            r0[3] = __float_as_uint(wy1a * wxA);
            r1[0] = o0 + 64; r1[1] = o1 + 64;
            r1[2] = __float_as_uint(wy0a * wxB);
            r1[3] = __float_as_uint(wy1a * wxB);
            *(u32x4*)(dst + c * 8)     = r0;
            *(u32x4*)(dst + c * 8 + 4) = r1;
        }
    }
    __syncthreads();

    // ---------------- phase 2 ----------------
    {
        const int d8 = tid & 3;
        const int xc = (tid >> 2) & 1;
        const int g  = tid >> 3;          // q*2 + h
        const int q  = g >> 1;
        const int h  = g & 1;
        const int H  = hp * 2 + h;
        const unsigned vbase = (unsigned)(H * HEAD_IMG_BYTES) + (unsigned)(d8 * 16);
        const char* vt = (const char*)value_t;
        const unsigned* iw = &s_iw[g * 132 + xc * 4];

        float acc[8] = {0.f, 0.f, 0.f, 0.f, 0.f, 0.f, 0.f, 0.f};
#pragma unroll
        for (int half = 0; half < 2; half++) {
            u32x2 off[8];
#pragma unroll
            for (int p = 0; p < 8; p++)
                off[p] = *(const u32x2*)(iw + (half * 8 + p) * 8);
            f16x8 v0[8], v1[8];
#pragma unroll
            for (int p = 0; p < 8; p++) {
                v0[p] = *(const f16x8*)(vt + (size_t)(vbase + off[p][0]));
                v1[p] = *(const f16x8*)(vt + (size_t)(vbase + off[p][1]));
            }
#pragma unroll
            for (int p = 0; p < 8; p++) {
                const f32x2 w = *(const f32x2*)(iw + (half * 8 + p) * 8 + 2);
#pragma unroll
                for (int r = 0; r < 8; r++) {
                    acc[r] = fmaf((float)v0[p][r], w[0], acc[r]);   // v_fma_mix_f32
                    acc[r] = fmaf((float)v1[p][r], w[1], acc[r]);
                }
            }
        }
#pragma unroll
        for (int j = 0; j < 8; j++) acc[j] += __shfl_xor(acc[j], 4);

        if (xc == 0) {
            s16x8 o = pack8(make_float4(acc[0], acc[1], acc[2], acc[3]),
                            make_float4(acc[4], acc[5], acc[6], acc[7]));
            *(s16x8*)(sampled + (size_t)(qbase + q) * 256 + H * 32 + d8 * 8) = o;
        }
    }
}

// ---------------------------------------------------------------------------
extern "C" void kernel_launch(void* const* d_in, const int* in_sizes, int n_in,
                              void* d_out, int out_size, void* d_ws, size_t ws_size,
                              hipStream_t stream) {
    const float* query  = (const float*)d_in[0];
    const float* refpts = (const float*)d_in[1];
    const float* input_flatten = (const float*)d_in[2];
    const float* W_off  = (const float*)d_in[5];
    const float* b_off  = (const float*)d_in[6];
    const float* W_attn = (const float*)d_in[7];
    const float* b_attn = (const float*)d_in[8];
    const float* W_val  = (const float*)d_in[9];
    const float* b_val  = (const float*)d_in[10];
    const float* W_out  = (const float*)d_in[11];
    const float* b_out  = (const float*)d_in[12];
    float* out = (float*)d_out;

    char* ws = (char*)d_ws;
    f16*            value_t = (f16*)ws;                                    // 8*Q*32 f16   = 11141120 B
    f16*            offattn = (f16*)(ws + 11141120);                       // Q*384 f16    = 16711680 B
    unsigned short* sampled = (unsigned short*)(ws + 27852800);            // Q*256 bf16   = 11141120 B
    unsigned short* w16     = (unsigned short*)(ws + 38993920);            // 229376 bf16
    float*          bias_cat= (float*)(ws + 39452672);                     // 384 f32

    cvt_weights<<<225, 256, 0, stream>>>(W_off, W_attn, W_val, W_out, b_off, b_attn, w16, bias_cat);

    // value_t + offattn in one dispatch (64x128 tiles, 5 slabs, 1700 blocks)
    gemm_proj<<<dim3(340, 5), 256, 0, stream>>>(input_flatten, query, w16,
                                                b_val, bias_cat, value_t, offattn);
    // bilinear sampling + attention-weighted sum
    sample_kernel<<<dim3((Q_TOTAL / QB) * 4), 256, 0, stream>>>(value_t, offattn, refpts, sampled);
    // out = sampled @ W_out^T + b_out
    gemm_out<<<dim3(340, 2), 256, 0, stream>>>(sampled, w16 + 163840, b_out, out);
}

// Round 13
// 80.019 us; speedup vs baseline: 1.0608x; 1.0017x over previous
//
#include <hip/hip_runtime.h>
#include <math.h>

#define Q_TOTAL 21760
#define QB 16        // queries per sampling block
#define HEAD_IMG_BYTES 1392640   // 21760 * 32 * 2  (one head's transposed image, f16)

typedef _Float16     f16;
typedef short        s16x8 __attribute__((ext_vector_type(8)));
typedef f16          f16x8 __attribute__((ext_vector_type(8)));
typedef f16          f16x4 __attribute__((ext_vector_type(4)));
typedef f16          f16x2 __attribute__((ext_vector_type(2)));
typedef __bf16       bfv8  __attribute__((ext_vector_type(8)));
typedef float        f32x4 __attribute__((ext_vector_type(4)));
typedef float        f32x2 __attribute__((ext_vector_type(2)));
typedef unsigned int u32x4 __attribute__((ext_vector_type(4)));
typedef unsigned int u32x2 __attribute__((ext_vector_type(2)));

// pack 8 floats -> 8 bf16 (RNE; compiler emits v_cvt_pk_bf16_f32)
__device__ __forceinline__ s16x8 pack8(float4 a, float4 b) {
    bfv8 t;
    t[0] = (__bf16)a.x; t[1] = (__bf16)a.y; t[2] = (__bf16)a.z; t[3] = (__bf16)a.w;
    t[4] = (__bf16)b.x; t[5] = (__bf16)b.y; t[6] = (__bf16)b.z; t[7] = (__bf16)b.w;
    return __builtin_bit_cast(s16x8, t);
}

// async 16B global -> LDS (dest = wave-uniform base + lane*16)
__device__ __forceinline__ void gload_lds16(const void* g, void* l) {
    auto gp = (const __attribute__((address_space(1))) unsigned int*)(g);
    auto lp = (__attribute__((address_space(3))) unsigned int*)(l);
    __builtin_amdgcn_global_load_lds(gp, lp, 16, 0, 0);
}

// ---------------------------------------------------------------------------
// Build pre-permuted bf16 weight tiles for global_load_lds staging.
// 56 tiles of 8192 B: t 0-7  = W_val rows 0-127   (proj slab 0), kt = (t&7)*32
//                     t 8-15 = W_val rows 128-255 (slab 1)
//                     t16-23 = W_off rows 0-127   (slab 2)
//                     t24-31 = W_off rows 128-255 (slab 3)
//                     t32-39 = W_attn             (slab 4)
//                     t40-47 = W_out rows 0-127   (out cslab 0)
//                     t48-55 = W_out rows 128-255 (out cslab 1)
// Tile byte layout: logical L = row*64 + kbyte stored at pi(L) = L ^ ((row&7)<<4)
// so a LINEAR global_load_lds fill + the GEMMs' swizzled ds_reads line up.
// ---------------------------------------------------------------------------
__global__ __launch_bounds__(256) void cvt_tiles(
    const float* __restrict__ Woff, const float* __restrict__ Wattn,
    const float* __restrict__ Wval, const float* __restrict__ Wout,
    unsigned short* __restrict__ w16t)
{
    const int c = blockIdx.x * 256 + threadIdx.x;   // 0..28671 (16B chunks)
    const int t = c >> 9;                           // tile id
    const int q = (c & 511) * 16;                   // logical byte in tile
    const int r = q >> 6;                           // row 0..127
    const int i = q & 63;                           // byte within 64B row
    const int dstb = t * 8192 + (q ^ ((r & 7) << 4));
    const int kelem = (t & 7) * 32 + (i >> 1);      // K element 0..255
    const float* src; int rowbase;
    if (t < 8)       { src = Wval;  rowbase = 0;   }
    else if (t < 16) { src = Wval;  rowbase = 128; }
    else if (t < 24) { src = Woff;  rowbase = 0;   }
    else if (t < 32) { src = Woff;  rowbase = 128; }
    else if (t < 40) { src = Wattn; rowbase = 0;   }
    else if (t < 48) { src = Wout;  rowbase = 0;   }
    else             { src = Wout;  rowbase = 128; }
    const float* p = src + (size_t)(rowbase + r) * 256 + kelem;
    s16x8 v = pack8(*(const float4*)p, *(const float4*)(p + 4));
    *(s16x8*)((char*)w16t + dstb) = v;
}

// ---------------------------------------------------------------------------
// Fused projection GEMM: BM=64, BN=128 slab, BK=32, 256 threads = 4 waves.
// grid (340, 5): slab 0-1: A=input_flatten -> value_t (f16, per-head transp.)
//                slab 2-4: A=query        -> offattn (f16)
// B staged via async global_load_lds from pre-permuted tiles (linear fill);
// A staged f32->bf16 in regs + swizzled ds_write (same XOR as reads).
// ---------------------------------------------------------------------------
__global__ __launch_bounds__(256) void gemm_proj(
    const float* __restrict__ input_flatten,
    const float* __restrict__ query,
    const unsigned short* __restrict__ w16t,
    const float* __restrict__ b_val,
    const float* __restrict__ b_off,
    const float* __restrict__ b_attn,
    f16* __restrict__ value_t,
    f16* __restrict__ offattn)
{
    constexpr int K = 256, BM = 64, BN = 128;
    constexpr int NB2 = BN / 2;
    constexpr int NF = NB2 / 16;
    __shared__ unsigned short As[BM * 32];
    __shared__ unsigned short Bs[BN * 32];

    const int tid  = threadIdx.x;
    const int lane = tid & 63;
    const int wv   = tid >> 6;
    const int wr   = wv >> 1, wc = wv & 1;
    const int rowBase = blockIdx.x * BM;
    const int slab = blockIdx.y;

    const float* A32 = (slab < 2) ? input_flatten : query;
    const float* bias;
    if (slab < 2)       bias = b_val + slab * 128;
    else if (slab == 2) bias = b_off;
    else if (slab == 3) bias = b_off + 128;
    else                bias = b_attn;

    const char* Btiles = (const char*)w16t + (size_t)slab * 65536; // 8 tiles of 8192B

    const int sr    = tid >> 2;          // A staging row 0..63
    const int skq   = (tid & 3) * 8;
    const int sslot = (tid & 3) * 16;
    const int wbase = wv * 1024;         // wave-uniform LDS byte base
    const int t16   = tid * 16;

    f32x4 acc[2][NF];
#pragma unroll
    for (int i = 0; i < 2; i++)
#pragma unroll
        for (int j = 0; j < NF; j++) acc[i][j] = (f32x4){0.f, 0.f, 0.f, 0.f};

    const float* Ap = A32 + (size_t)(rowBase + sr) * K + skq;

    for (int kti = 0; kti < 8; kti++) {
        const int kt = kti * 32;
        s16x8 aval = pack8(*(const float4*)(Ap + kt), *(const float4*)(Ap + kt + 4));
        __syncthreads();
        // async B tile fill: linear LDS, pre-permuted source
        const char* bsrc = Btiles + kti * 8192;
        gload_lds16(bsrc + t16,        (char*)Bs + wbase);
        gload_lds16(bsrc + 4096 + t16, (char*)Bs + 4096 + wbase);
        // A tile: swizzled ds_write
        *(s16x8*)((char*)As + ((sr * 64 + sslot) ^ ((sr & 7) << 4))) = aval;
        __syncthreads();   // drains vmcnt (B) + lgkmcnt (A)
        s16x8 af[2];
#pragma unroll
        for (int mi = 0; mi < 2; mi++) {
            const int row = wr * 32 + mi * 16 + (lane & 15);
            af[mi] = *(const s16x8*)((char*)As + ((row * 64 + (lane >> 4) * 16) ^ ((row & 7) << 4)));
        }
#pragma unroll
        for (int ni = 0; ni < NF; ni++) {
            const int row = wc * NB2 + ni * 16 + (lane & 15);
            s16x8 bfrag = *(const s16x8*)((char*)Bs + ((row * 64 + (lane >> 4) * 16) ^ ((row & 7) << 4)));
#pragma unroll
            for (int mi = 0; mi < 2; mi++)
                acc[mi][ni] = __builtin_amdgcn_mfma_f32_16x16x32_bf16(af[mi], bfrag, acc[mi][ni], 0, 0, 0);
        }
    }

#pragma unroll
    for (int ni = 0; ni < NF; ni++) {
        const int localcol = wc * NB2 + ni * 16 + (lane & 15);
        const float bv = bias[localcol];
#pragma unroll
        for (int mi = 0; mi < 2; mi++) {
            const int r0 = rowBase + wr * 32 + mi * 16 + (lane >> 4) * 4;
#pragma unroll
            for (int j = 0; j < 4; j++) {
                const float v = acc[mi][ni][j] + bv;
                const int row = r0 + j;
                if (slab < 2) {
                    const int col = slab * 128 + localcol;
                    value_t[((size_t)(col >> 5) * Q_TOTAL + row) * 32 + (col & 31)] = (f16)v;
                } else {
                    const int col = (slab - 2) * 128 + localcol;
                    offattn[(size_t)row * 384 + col] = (f16)v;
                }
            }
        }
    }
}

// ---------------------------------------------------------------------------
// Output GEMM: out[Q][256] f32 = sampled(bf16) @ W_out^T + b_out.
// BM=64, BN=128, grid (340, 2). B via global_load_lds (tiles 40-55).
// ---------------------------------------------------------------------------
__global__ __launch_bounds__(256) void gemm_out(
    const unsigned short* __restrict__ A16,      // sampled bf16 [Q][256]
    const unsigned short* __restrict__ w16t,
    const float* __restrict__ bias,
    float* __restrict__ C)
{
    constexpr int K = 256, BM = 64, BN = 128;
    constexpr int NB2 = BN / 2;
    constexpr int NF = NB2 / 16;
    __shared__ unsigned short As[BM * 32];
    __shared__ unsigned short Bs[BN * 32];

    const int tid  = threadIdx.x;
    const int lane = tid & 63;
    const int wv   = tid >> 6;
    const int wr   = wv >> 1, wc = wv & 1;
    const int rowBase = blockIdx.x * BM;
    const int colBase = blockIdx.y * BN;

    const char* Btiles = (const char*)w16t + 327680 + (size_t)blockIdx.y * 65536;

    const int sr    = tid >> 2;
    const int skq   = (tid & 3) * 8;
    const int sslot = (tid & 3) * 16;
    const int wbase = wv * 1024;
    const int t16   = tid * 16;

    f32x4 acc[2][NF];
#pragma unroll
    for (int i = 0; i < 2; i++)
#pragma unroll
        for (int j = 0; j < NF; j++) acc[i][j] = (f32x4){0.f, 0.f, 0.f, 0.f};

    const unsigned short* Ap = A16 + (size_t)(rowBase + sr) * K + skq;

    for (int kti = 0; kti < 8; kti++) {
        const int kt = kti * 32;
        s16x8 aval = *(const s16x8*)(Ap + kt);
        __syncthreads();
        const char* bsrc = Btiles + kti * 8192;
        gload_lds16(bsrc + t16,        (char*)Bs + wbase);
        gload_lds16(bsrc + 4096 + t16, (char*)Bs + 4096 + wbase);
        *(s16x8*)((char*)As + ((sr * 64 + sslot) ^ ((sr & 7) << 4))) = aval;
        __syncthreads();
        s16x8 af[2];
#pragma unroll
        for (int mi = 0; mi < 2; mi++) {
            const int row = wr * 32 + mi * 16 + (lane & 15);
            af[mi] = *(const s16x8*)((char*)As + ((row * 64 + (lane >> 4) * 16) ^ ((row & 7) << 4)));
        }
#pragma unroll
        for (int ni = 0; ni < NF; ni++) {
            const int row = wc * NB2 + ni * 16 + (lane & 15);
            s16x8 bfrag = *(const s16x8*)((char*)Bs + ((row * 64 + (lane >> 4) * 16) ^ ((row & 7) << 4)));
#pragma unroll
            for (int mi = 0; mi < 2; mi++)
                acc[mi][ni] = __builtin_amdgcn_mfma_f32_16x16x32_bf16(af[mi], bfrag, acc[mi][ni], 0, 0, 0);
        }
    }

#pragma unroll
    for (int ni = 0; ni < NF; ni++) {
        const int col = colBase + wc * NB2 + ni * 16 + (lane & 15);
        const float bv = bias[col];
#pragma unroll
        for (int mi = 0; mi < 2; mi++) {
            const int r0 = rowBase + wr * 32 + mi * 16 + (lane >> 4) * 4;
#pragma unroll
            for (int j = 0; j < 4; j++)
                C[(size_t)(r0 + j) * 256 + col] = acc[mi][ni][j] + bv;
        }
    }
}

// ---------------------------------------------------------------------------
// Sampling: block = 16 queries x 2 heads (256 threads).  [unchanged from r9]
// At its structural floor (~39 us): random-gather L2 throughput.
// ---------------------------------------------------------------------------
__global__ __launch_bounds__(256) void sample_kernel(
    const f16* __restrict__ value_t,             // [8][Q][32] f16
    const f16* __restrict__ offattn,             // [Q][384] f16
    const float* __restrict__ refpts,            // [Q][4][2] f32
    unsigned short* __restrict__ sampled)        // [Q][256] bf16
{
    __shared__ __attribute__((aligned(16))) unsigned s_iw[32 * 132];

    const int tid   = threadIdx.x;
    const int qt    = blockIdx.x >> 2;
    const int hp    = blockIdx.x & 3;
    const int qbase = qt * QB;

    // ---------------- phase 1 ----------------
    {
        const int q  = tid >> 4;
        const int h  = (tid >> 3) & 1;
        const int l  = (tid >> 1) & 3;
        const int ph = tid & 1;
        const int H  = hp * 2 + h;
        const int g  = tid >> 3;         // q*2 + h
        const f16* oa = offattn + (size_t)(qbase + q) * 384;

        f16x2 lgh = *(const f16x2*)(oa + 256 + H * 16 + l * 4 + ph * 2);
        const float lg0 = (float)lgh[0], lg1 = (float)lgh[1];
        float m = fmaxf(lg0, lg1);
        m = fmaxf(m, __shfl_xor(m, 1));
        m = fmaxf(m, __shfl_xor(m, 2));
        m = fmaxf(m, __shfl_xor(m, 4));
        float e0 = __expf(lg0 - m), e1 = __expf(lg1 - m);
        float s = e0 + e1;
        s += __shfl_xor(s, 1);
        s += __shfl_xor(s, 2);
        s += __shfl_xor(s, 4);
        const float inv = 1.f / s;
        const float aw2[2] = {e0 * inv, e1 * inv};

        f16x4 offh = *(const f16x4*)(oa + H * 32 + l * 8 + ph * 4);
        f32x2 rp = *(const f32x2*)(refpts + (size_t)(qbase + q) * 8 + l * 2);

        const int   SZ[4] = {128, 64, 32, 16};
        const int   ST[4] = {0, 16384, 20480, 21504};
        const int   W_ = SZ[l], START = ST[l];
        const float S = (float)W_;

        unsigned* dst = &s_iw[g * 132 + (l * 4 + ph * 2) * 8];
#pragma unroll
        for (int c = 0; c < 2; c++) {
            const float ox = (float)offh[c * 2], oy = (float)offh[c * 2 + 1];
            const float a = aw2[c];
            const float gx = fmaf(rp[0], S, ox) - 0.5f;
            const float gy = fmaf(rp[1], S, oy) - 0.5f;
            const float x0f = floorf(gx), y0f = floorf(gy);
            const float lx = gx - x0f, ly = gy - y0f;
            const int x0 = (int)x0f, y0 = (int)y0f;
            const int xs  = min(max(x0, 0), W_ - 2);
            const int sft = xs - x0;
            const float wx0 = (x0 >= 0 && x0 < W_) ? (1.f - lx) : 0.f;
            const float wx1 = (x0 + 1 >= 0 && x0 + 1 < W_) ? lx : 0.f;
            const float wxA = (sft == 0) ? wx0 : ((sft == 1) ? wx1 : 0.f);
            const float wxB = (sft == 0) ? wx1 : ((sft == -1) ? wx0 : 0.f);
            const int y1 = y0 + 1;
            const int y0c = min(max(y0, 0), W_ - 1);
            const int y1c = min(max(y1, 0), W_ - 1);
            const float wy0a = (((y0 >= 0) && (y0 < W_)) ? (1.f - ly) : 0.f) * a;
            const float wy1a = (((y1 >= 0) && (y1 < W_)) ? ly : 0.f) * a;
            const unsigned o0 = (unsigned)((START + y0c * W_ + xs) * 64);
            const unsigned o1 = (unsigned)((START + y1c * W_ + xs) * 64);
            u32x4 r0, r1;
            r0[0] = o0;      r0[1] = o1;
            r0[2] = __float_as_uint(wy0a * wxA);
            r0[3] = __float_as_uint(wy1a * wxA);
            r1[0] = o0 + 64; r1[1] = o1 + 64;
            r1[2] = __float_as_uint(wy0a * wxB);
            r1[3] = __float_as_uint(wy1a * wxB);
            *(u32x4*)(dst + c * 8)     = r0;
            *(u32x4*)(dst + c * 8 + 4) = r1;
        }
    }
    __syncthreads();

    // ---------------- phase 2 ----------------
    {
        const int d8 = tid & 3;
        const int xc = (tid >> 2) & 1;
        const int g  = tid >> 3;          // q*2 + h
        const int q  = g >> 1;
        const int h  = g & 1;
        const int H  = hp * 2 + h;
        const unsigned vbase = (unsigned)(H * HEAD_IMG_BYTES) + (unsigned)(d8 * 16);
        const char* vt = (const char*)value_t;
        const unsigned* iw = &s_iw[g * 132 + xc * 4];

        float acc[8] = {0.f, 0.f, 0.f, 0.f, 0.f, 0.f, 0.f, 0.f};
#pragma unroll
        for (int half = 0; half < 2; half++) {
            u32x2 off[8];
#pragma unroll
            for (int p = 0; p < 8; p++)
                off[p] = *(const u32x2*)(iw + (half * 8 + p) * 8);
            f16x8 v0[8], v1[8];
#pragma unroll
            for (int p = 0; p < 8; p++) {
                v0[p] = *(const f16x8*)(vt + (size_t)(vbase + off[p][0]));
                v1[p] = *(const f16x8*)(vt + (size_t)(vbase + off[p][1]));
            }
#pragma unroll
            for (int p = 0; p < 8; p++) {
                const f32x2 w = *(const f32x2*)(iw + (half * 8 + p) * 8 + 2);
#pragma unroll
                for (int r = 0; r < 8; r++) {
                    acc[r] = fmaf((float)v0[p][r], w[0], acc[r]);   // v_fma_mix_f32
                    acc[r] = fmaf((float)v1[p][r], w[1], acc[r]);
                }
            }
        }
#pragma unroll
        for (int j = 0; j < 8; j++) acc[j] += __shfl_xor(acc[j], 4);

        if (xc == 0) {
            s16x8 o = pack8(make_float4(acc[0], acc[1], acc[2], acc[3]),
                            make_float4(acc[4], acc[5], acc[6], acc[7]));
            *(s16x8*)(sampled + (size_t)(qbase + q) * 256 + H * 32 + d8 * 8) = o;
        }
    }
}

// ---------------------------------------------------------------------------
extern "C" void kernel_launch(void* const* d_in, const int* in_sizes, int n_in,
                              void* d_out, int out_size, void* d_ws, size_t ws_size,
                              hipStream_t stream) {
    const float* query  = (const float*)d_in[0];
    const float* refpts = (const float*)d_in[1];
    const float* input_flatten = (const float*)d_in[2];
    const float* W_off  = (const float*)d_in[5];
    const float* b_off  = (const float*)d_in[6];
    const float* W_attn = (const float*)d_in[7];
    const float* b_attn = (const float*)d_in[8];
    const float* W_val  = (const float*)d_in[9];
    const float* b_val  = (const float*)d_in[10];
    const float* W_out  = (const float*)d_in[11];
    const float* b_out  = (const float*)d_in[12];
    float* out = (float*)d_out;

    char* ws = (char*)d_ws;
    f16*            value_t = (f16*)ws;                                    // 8*Q*32 f16   = 11141120 B
    f16*            offattn = (f16*)(ws + 11141120);                       // Q*384 f16    = 16711680 B
    unsigned short* sampled = (unsigned short*)(ws + 27852800);            // Q*256 bf16   = 11141120 B
    unsigned short* w16t    = (unsigned short*)(ws + 38993920);            // 56 tiles * 8192 B

    cvt_tiles<<<112, 256, 0, stream>>>(W_off, W_attn, W_val, W_out, w16t);

    // value_t + offattn in one dispatch (64x128 tiles, 5 slabs, 1700 blocks)
    gemm_proj<<<dim3(340, 5), 256, 0, stream>>>(input_flatten, query, w16t,
                                                b_val, b_off, b_attn, value_t, offattn);
    // bilinear sampling + attention-weighted sum
    sample_kernel<<<dim3((Q_TOTAL / QB) * 4), 256, 0, stream>>>(value_t, offattn, refpts, sampled);
    // out = sampled @ W_out^T + b_out
    gemm_out<<<dim3(340, 2), 256, 0, stream>>>(sampled, w16t, b_out, out);
}